// Round 7
// baseline (1714.904 us; speedup 1.0000x reference)
//
#include <hip/hip_runtime.h>
#include <hip/hip_fp16.h>

#define S_LEN 512
#define BATCH 32
#define CHUNK 16

typedef _Float16 hv2  __attribute__((ext_vector_type(2)));
typedef _Float16 half8 __attribute__((ext_vector_type(8)));
typedef float    f32x4 __attribute__((ext_vector_type(4)));

__device__ __forceinline__ float dot2f(hv2 a, hv2 b, float c) {
#if __has_builtin(__builtin_amdgcn_fdot2)
    return __builtin_amdgcn_fdot2(a, b, c, false);
#else
    return c + (float)a.x * (float)b.x + (float)a.y * (float)b.y;
#endif
}

__device__ __forceinline__ float fast_tanh(float x) {
    float e = __expf(2.f * x);
    return 1.f - 2.f / (e + 1.f);
}

// Step barrier that does NOT drain vmcnt: LDS-only visibility.
__device__ __forceinline__ void lds_barrier() {
    __asm__ volatile("s_waitcnt lgkmcnt(0)\n\ts_barrier" ::: "memory");
}
__device__ __forceinline__ void vm_drain() {
    __asm__ volatile("s_waitcnt vmcnt(0)" ::: "memory");
}

// flags map (128 uints at workspace head):
//  [0..31]  producer progress (t) per batch
//  [64]     gemm in-order publish counter (chunk-quarters)
#define F_GCTR 64

// ---------------------------------------------------------------------------
// Prep: convert to padded f16 (relu fused for emb). Zeroes flags.
// ---------------------------------------------------------------------------
#define E8   1280000   // 32000*320/8
#define W18  64000     // 320*1600/8
#define W28  12800     // 320*320/8
#define FF8  5120      // 128*320/8
#define PREP_TOTAL8 (E8 + W18 + W28 + FF8 + FF8)

__global__ __launch_bounds__(256) void k_prep(
    const float* __restrict__ emb,  const float* __restrict__ Wih1,
    const float* __restrict__ Wih2, const float* __restrict__ fc1w,
    const float* __restrict__ fc2w,
    _Float16* __restrict__ embf, _Float16* __restrict__ Wf1,
    _Float16* __restrict__ Wf2,  _Float16* __restrict__ F1,
    _Float16* __restrict__ F2,   unsigned int* __restrict__ flags)
{
    int gid = blockIdx.x * 256 + threadIdx.x;
    if (gid < 128) flags[gid] = 0u;
    if (gid >= PREP_TOTAL8) return;

    half8 v;
    _Float16* dst;

    if (gid < E8) {
        int row = gid / 40, c8 = (gid - row * 40) * 8;
        #pragma unroll
        for (int j = 0; j < 8; ++j) {
            int c = c8 + j;
            float f = (c < 300) ? emb[(size_t)row * 300 + c] : 0.f;
            v[j] = (_Float16)(f > 0.f ? f : 0.f);
        }
        dst = embf + (size_t)gid * 8;
    } else if (gid < E8 + W18) {
        int i = gid - E8;
        int row = i / 200, c8 = (i - row * 200) * 8;
        #pragma unroll
        for (int j = 0; j < 8; ++j) {
            int c = c8 + j, w = c / 320, cc = c - w * 320;
            float f = (row < 300 && cc < 300) ? Wih1[(size_t)row * 1500 + w * 300 + cc] : 0.f;
            v[j] = (_Float16)f;
        }
        dst = Wf1 + (size_t)i * 8;
    } else if (gid < E8 + W18 + W28) {
        int i = gid - E8 - W18;
        int row = i / 40, c8 = (i - row * 40) * 8;
        #pragma unroll
        for (int j = 0; j < 8; ++j) {
            int c = c8 + j;
            float f = (row < 300 && c < 300) ? Wih2[(size_t)row * 300 + c] : 0.f;
            v[j] = (_Float16)f;
        }
        dst = Wf2 + (size_t)i * 8;
    } else if (gid < E8 + W18 + W28 + FF8) {
        int i = gid - E8 - W18 - W28;
        int row = i / 40, c8 = (i - row * 40) * 8;
        #pragma unroll
        for (int j = 0; j < 8; ++j) {
            int c = c8 + j;
            v[j] = (_Float16)((c < 300) ? fc1w[(size_t)row * 300 + c] : 0.f);
        }
        dst = F1 + (size_t)i * 8;
    } else {
        int i = gid - E8 - W18 - W28 - FF8;
        int row = i / 40, c8 = (i - row * 40) * 8;
        #pragma unroll
        for (int j = 0; j < 8; ++j) {
            int c = c8 + j;
            v[j] = (_Float16)((c < 300) ? fc2w[(size_t)row * 300 + c] : 0.f);
        }
        dst = F2 + (size_t)i * 8;
    }
    *(half8*)dst = v;
}

// ---------------------------------------------------------------------------
// Fused pipeline kernel. 192 blocks x 512 threads, all co-resident.
//  Blocks 0..31   : producer, layer 1 (per-batch) + fused fc1 epilogue.
//  Blocks 32..63  : consumer, layer 2 (per-batch) + fused fc2 epilogue
//                   (epilogue runs BEFORE the producer-poll -> hidden).
//  Blocks 64..191 : GEMM1 role, 4 blocks per U-chunk, self-throttled ordered
//                   pipeline via flags[F_GCTR] (chunk c gated on c-GDEPTH).
// H2 never touches global memory (fc2 consumes the LDS h-ring directly), so
// EMBF is read-only after prep — the R6 alias race is structurally gone.
// Dynamic LDS (rec blocks): same layout as R0.
// ---------------------------------------------------------------------------
#define LDS_BYTES 52096
#define NREC 64
#define NGEMM 128
#define GDEPTH 4

__device__ __forceinline__ void load_u_regs(float* up, const float* __restrict__ U1,
                                            int b, int t0) {
    #pragma unroll
    for (int j = 0; j < 10; ++j) {
        int e = threadIdx.x + 512 * j;
        int row = e / 300, col = e - row * 300;
        up[j] = (e < 4800) ? U1[((size_t)((t0 + row) * BATCH + b)) * 300 + col] : 0.f;
    }
}

__device__ __forceinline__ void wait_gemm(unsigned int* flags, int c) {
    if (threadIdx.x == 0) {
        while (__hip_atomic_load(&flags[F_GCTR], __ATOMIC_ACQUIRE,
                                 __HIP_MEMORY_SCOPE_AGENT) < 4u * (unsigned)(c + 1))
            __builtin_amdgcn_s_sleep(2);
    }
    __syncthreads();
}

// Fused FC epilogue: out rows (b*512 + tb + 0..15) x 128 cols from the LDS
// h-ring (chunk held in hc). Same MFMA layout as the proven k_fc kernel:
// A-frag row = lane&15 (= h slot), B-frag row = lane&15 (= out col),
// D row = (lane>>4)*4+reg (= h slot), col = lane&15. Wave w owns n-tile w.
__device__ __forceinline__ void fc_epilogue(
    const _Float16 (*hc)[320], const _Float16* __restrict__ F,
    const float* __restrict__ fb, float* __restrict__ out,
    int b, int tb, int wid, int lm, int lq)
{
    f32x4 acc = (f32x4){0.f, 0.f, 0.f, 0.f};
    const int n = wid * 16 + lm;
    const _Float16* frow = F + (size_t)n * 320;
    #pragma unroll
    for (int k0 = 0; k0 < 320; k0 += 32) {
        half8 a  = *(const half8*)&hc[lm][k0 + lq * 8];
        half8 bf = *(const half8*)&frow[k0 + lq * 8];
        acc = __builtin_amdgcn_mfma_f32_16x16x32_f16(a, bf, acc, 0, 0, 0);
    }
    const float bv = fb[n];
    #pragma unroll
    for (int reg = 0; reg < 4; ++reg) {
        const int t = tb + lq * 4 + reg;
        out[(size_t)(b * 512 + t) * 128 + n] = acc[reg] + bv;
    }
}

__global__ __launch_bounds__(512) void k_rec_fused(
    const int* __restrict__ x, const _Float16* __restrict__ embf,
    const _Float16* __restrict__ Wf1,
    const float* __restrict__ bih1, const float* __restrict__ bhh1,
    float* __restrict__ U1, const float* __restrict__ Whh1,
    const _Float16* __restrict__ Wf2, const float* __restrict__ Whh2,
    const float* __restrict__ bih2, const float* __restrict__ bhh2,
    _Float16* __restrict__ H1f,
    const _Float16* __restrict__ F1, const _Float16* __restrict__ F2,
    const float* __restrict__ fb1, const float* __restrict__ fb2,
    float* __restrict__ out1, float* __restrict__ out2,
    unsigned int* __restrict__ flags)
{
    const int tid  = threadIdx.x;

    if (blockIdx.x >= NREC) {
        // ===================== GEMM1 role (ordered pipeline) =====================
        const int gi   = blockIdx.x - NREC;   // 0..127
        const int cch  = gi >> 2;             // U chunk 0..31
        const int sub  = gi & 3;

        if (cch >= GDEPTH) {                  // self-throttle: keep chunk order
            if (tid == 0) {
                while (__hip_atomic_load(&flags[F_GCTR], __ATOMIC_ACQUIRE,
                                         __HIP_MEMORY_SCOPE_AGENT) <
                       4u * (unsigned)(cch - GDEPTH + 1))
                    __builtin_amdgcn_s_sleep(2);
            }
            __syncthreads();
        }

        const int wid  = tid >> 6;            // 0..7
        const int lane = tid & 63;
        const int m    = lane & 15;
        const int q    = lane >> 4;
        const int r0   = cch * 512 + (sub >> 1) * 256 + wid * 32;
        const int n0   = (sub & 1) * 160;

        f32x4 acc[2][10];
        #pragma unroll
        for (int a = 0; a < 2; ++a)
            #pragma unroll
            for (int j = 0; j < 10; ++j)
                acc[a][j] = (f32x4){0.f, 0.f, 0.f, 0.f};

        const int rA = r0 + m, rB = r0 + 16 + m;
        const int xbA = ((rA & 31) * S_LEN + (rA >> 5)) * 5;
        const int xbB = ((rB & 31) * S_LEN + (rB >> 5)) * 5;

        for (int w = 0; w < 5; ++w) {
            const int idxA = x[xbA + w];
            const int idxB = x[xbB + w];
            const _Float16* ea = embf + (size_t)idxA * 320;
            const _Float16* eb = embf + (size_t)idxB * 320;
            const _Float16* wb = Wf1 + (size_t)w * 320;
            #pragma unroll
            for (int c = 0; c < 10; ++c) {
                const int k = c * 32 + q * 8;
                half8 a0 = *(const half8*)(ea + k);
                half8 a1 = *(const half8*)(eb + k);
                #pragma unroll
                for (int nt = 0; nt < 10; ++nt) {
                    half8 bf = *(const half8*)(wb + (size_t)(n0 + nt * 16 + m) * 1600 + k);
                    acc[0][nt] = __builtin_amdgcn_mfma_f32_16x16x32_f16(a0, bf, acc[0][nt], 0, 0, 0);
                    acc[1][nt] = __builtin_amdgcn_mfma_f32_16x16x32_f16(a1, bf, acc[1][nt], 0, 0, 0);
                }
            }
        }

        #pragma unroll
        for (int nt = 0; nt < 10; ++nt) {
            const int n = n0 + nt * 16 + m;
            if (n >= 300) continue;
            const float bias = bih1[n] + bhh1[n];
            #pragma unroll
            for (int mt = 0; mt < 2; ++mt) {
                const int rbase = r0 + mt * 16 + q * 4;
                #pragma unroll
                for (int reg = 0; reg < 4; ++reg)
                    U1[(size_t)(rbase + reg) * 300 + n] = acc[mt][nt][reg] + bias;
            }
        }
        vm_drain();
        __syncthreads();   // all waves' stores complete before publish
        if (tid == 0) {
            while (__hip_atomic_load(&flags[F_GCTR], __ATOMIC_ACQUIRE,
                                     __HIP_MEMORY_SCOPE_AGENT) < 4u * (unsigned)cch)
                __builtin_amdgcn_s_sleep(1);
            __hip_atomic_fetch_add(&flags[F_GCTR], 1u,
                                   __ATOMIC_ACQ_REL, __HIP_MEMORY_SCOPE_AGENT);
        }
        return;
    }

    extern __shared__ char smem[];
    float   (*partials)[304] = (float(*)[304])smem;
    _Float16 (*hc)[320]      = (_Float16(*)[320])(smem + 12160);
    float   (*uc)[304]       = (float(*)[304])(smem + 22400);
    _Float16 (*h1s)[320]     = (_Float16(*)[320])(smem + 41856);

    const bool comp = tid < 500;
    const int g    = comp ? tid / 50 : 0;
    const int rt   = comp ? tid % 50 : 0;
    const int lane = tid & 63;
    const int wid  = tid >> 6;
    const int lm   = lane & 15;
    const int lq   = lane >> 4;

    // zero h ring (slot 15 = h_{-1} = 0; pad cols stay 0 forever)
    for (int i = tid; i < CHUNK * 320; i += 512)
        ((_Float16*)hc)[i] = (_Float16)0.f;

    if (blockIdx.x < 32) {
        // ========================= producer: layer 1 + fc1 =========================
        const int b = blockIdx.x;
        hv2 w1[6][16];
        if (comp) {
            #pragma unroll
            for (int i = 0; i < 6; ++i) {
                const float* wr = Whh1 + (size_t)(rt + 50 * i) * 300 + g * 32;
                #pragma unroll
                for (int j = 0; j < 16; ++j) {
                    int c0 = g * 32 + 2 * j;
                    hv2 p;
                    p.x = (c0     < 300) ? (_Float16)wr[2 * j]     : (_Float16)0.f;
                    p.y = (c0 + 1 < 300) ? (_Float16)wr[2 * j + 1] : (_Float16)0.f;
                    w1[i][j] = p;
                }
            }
        }

        wait_gemm(flags, 0);
        float upref[10];
        load_u_regs(upref, U1, b, 0);

        for (int c = 0; c < 32; ++c) {
            const int t0 = c * CHUNK;
            if (c > 0) {
                // bulk-store previous chunk's H1 + fused fc1 on the same chunk
                const int tb = t0 - CHUNK;
                for (int i = tid; i < CHUNK * 40; i += 512) {
                    int row = i / 40, c8 = i - row * 40;
                    half8 v = *(const half8*)&hc[row][c8 * 8];
                    *(half8*)&H1f[((size_t)((tb + row) * BATCH + b)) * 320 + c8 * 8] = v;
                }
                fc_epilogue(hc, F1, fb1, out1, b, tb, wid, lm, lq);
            }
            // stage this chunk's U into LDS from prefetch regs
            #pragma unroll
            for (int j = 0; j < 10; ++j) {
                int e = tid + 512 * j;
                if (e < 4800) {
                    int row = e / 300, col = e - row * 300;
                    uc[row][col] = upref[j];
                }
            }
            if (c > 0) {
                vm_drain();       // own H1 stores complete
                __syncthreads();  // all waves' stores complete before release
                if (tid == 0)
                    __hip_atomic_store(&flags[b], (unsigned)t0,
                                       __ATOMIC_RELEASE, __HIP_MEMORY_SCOPE_AGENT);
            }
            if (c + 1 < 32) {
                wait_gemm(flags, c + 1);                 // U1 chunk c+1 ready?
                load_u_regs(upref, U1, b, t0 + CHUNK);   // in flight across steps
            }
            lds_barrier();

            for (int s = 0; s < CHUNK; ++s) {
                if (comp) {
                    const half8* hp = (const half8*)&hc[(s - 1) & 15][g * 32];
                    float a0 = 0.f, a1 = 0.f, a2 = 0.f, a3 = 0.f, a4 = 0.f, a5 = 0.f;
                    #pragma unroll
                    for (int jj = 0; jj < 4; ++jj) {
                        half8 q8 = hp[jj];
                        const hv2* qv = (const hv2*)&q8;
                        #pragma unroll
                        for (int j4 = 0; j4 < 4; ++j4) {
                            const int j = 4 * jj + j4;
                            a0 = dot2f(w1[0][j], qv[j4], a0);
                            a1 = dot2f(w1[1][j], qv[j4], a1);
                            a2 = dot2f(w1[2][j], qv[j4], a2);
                            a3 = dot2f(w1[3][j], qv[j4], a3);
                            a4 = dot2f(w1[4][j], qv[j4], a4);
                            a5 = dot2f(w1[5][j], qv[j4], a5);
                        }
                    }
                    partials[g][rt]       = a0;
                    partials[g][rt + 50]  = a1;
                    partials[g][rt + 100] = a2;
                    partials[g][rt + 150] = a3;
                    partials[g][rt + 200] = a4;
                    partials[g][rt + 250] = a5;
                }
                lds_barrier();
                if (tid < 300) {
                    float ssum = uc[s][tid];
                    #pragma unroll
                    for (int g2 = 0; g2 < 10; ++g2)
                        ssum += partials[g2][tid];
                    hc[s][tid] = (_Float16)fast_tanh(ssum);
                }
                lds_barrier();
            }
        }
        // final chunk: store H1, flag, fused fc1
        {
            const int tb = S_LEN - CHUNK;
            for (int i = tid; i < CHUNK * 40; i += 512) {
                int row = i / 40, c8 = i - row * 40;
                half8 v = *(const half8*)&hc[row][c8 * 8];
                *(half8*)&H1f[((size_t)((tb + row) * BATCH + b)) * 320 + c8 * 8] = v;
            }
            fc_epilogue(hc, F1, fb1, out1, b, tb, wid, lm, lq);
            vm_drain();
            __syncthreads();
            if (tid == 0)
                __hip_atomic_store(&flags[b], (unsigned)S_LEN,
                                   __ATOMIC_RELEASE, __HIP_MEMORY_SCOPE_AGENT);
        }
    } else {
        // ========================= consumer: layer 2 + fc2 =========================
        const int b = blockIdx.x - 32;
        hv2 whh[6][16];
        if (comp) {
            #pragma unroll
            for (int i = 0; i < 6; ++i) {
                const float* wr = Whh2 + (size_t)(rt + 50 * i) * 300 + g * 32;
                #pragma unroll
                for (int j = 0; j < 16; ++j) {
                    int c0 = g * 32 + 2 * j;
                    hv2 p;
                    p.x = (c0     < 300) ? (_Float16)wr[2 * j]     : (_Float16)0.f;
                    p.y = (c0 + 1 < 300) ? (_Float16)wr[2 * j + 1] : (_Float16)0.f;
                    whh[i][j] = p;
                }
            }
        }
        float bias = (tid < 300) ? (bih2[tid] + bhh2[tid]) : 0.f;

        for (int c = 0; c < 32; ++c) {
            const int t0 = c * CHUNK;
            if (c > 0) {
                // fused fc2 on previous chunk's h2 (still in hc ring);
                // runs before the producer poll, so it's hidden under the wait
                fc_epilogue(hc, F2, fb2, out2, b, t0 - CHUNK, wid, lm, lq);
            }
            if (tid == 0) {
                while (__hip_atomic_load(&flags[b], __ATOMIC_ACQUIRE,
                                         __HIP_MEMORY_SCOPE_AGENT) < (unsigned)(t0 + CHUNK))
                    __builtin_amdgcn_s_sleep(2);
            }
            __syncthreads();   // orders after poll

            // stage this chunk's h1 into LDS
            for (int i = tid; i < CHUNK * 40; i += 512) {
                int row = i / 40, c8 = i - row * 40;
                *(half8*)&h1s[row][c8 * 8] =
                    *(const half8*)&H1f[((size_t)((t0 + row) * BATCH + b)) * 320 + c8 * 8];
            }
            lds_barrier();

            // U2-chunk = h1s @ Wf2^T via MFMA (M=16 steps, N=304, K=320)
            for (int nt = wid; nt < 19; nt += 8) {
                f32x4 acc = (f32x4){0.f, 0.f, 0.f, 0.f};
                const int n = nt * 16 + lm;
                const _Float16* wrow = Wf2 + (size_t)n * 320;
                #pragma unroll
                for (int k0 = 0; k0 < 320; k0 += 32) {
                    half8 a  = *(const half8*)&h1s[lm][k0 + lq * 8];
                    half8 bf = *(const half8*)&wrow[k0 + lq * 8];
                    acc = __builtin_amdgcn_mfma_f32_16x16x32_f16(a, bf, acc, 0, 0, 0);
                }
                #pragma unroll
                for (int reg = 0; reg < 4; ++reg)
                    uc[lq * 4 + reg][n] = acc[reg];
            }
            lds_barrier();

            for (int s = 0; s < CHUNK; ++s) {
                if (comp) {
                    const half8* hp = (const half8*)&hc[(s - 1) & 15][g * 32];
                    float a0 = 0.f, a1 = 0.f, a2 = 0.f, a3 = 0.f, a4 = 0.f, a5 = 0.f;
                    #pragma unroll
                    for (int jj = 0; jj < 4; ++jj) {
                        half8 q8 = hp[jj];
                        const hv2* qv = (const hv2*)&q8;
                        #pragma unroll
                        for (int j4 = 0; j4 < 4; ++j4) {
                            const int j = 4 * jj + j4;
                            a0 = dot2f(whh[0][j], qv[j4], a0);
                            a1 = dot2f(whh[1][j], qv[j4], a1);
                            a2 = dot2f(whh[2][j], qv[j4], a2);
                            a3 = dot2f(whh[3][j], qv[j4], a3);
                            a4 = dot2f(whh[4][j], qv[j4], a4);
                            a5 = dot2f(whh[5][j], qv[j4], a5);
                        }
                    }
                    partials[g][rt]       = a0;
                    partials[g][rt + 50]  = a1;
                    partials[g][rt + 100] = a2;
                    partials[g][rt + 150] = a3;
                    partials[g][rt + 200] = a4;
                    partials[g][rt + 250] = a5;
                }
                lds_barrier();
                if (tid < 300) {
                    float ssum = bias + uc[s][tid];
                    #pragma unroll
                    for (int g2 = 0; g2 < 10; ++g2)
                        ssum += partials[g2][tid];
                    hc[s][tid] = (_Float16)fast_tanh(ssum);
                }
                lds_barrier();
            }
        }
        // final chunk: fused fc2 (h2 chunk 31 in hc ring)
        fc_epilogue(hc, F2, fb2, out2, b, S_LEN - CHUNK, wid, lm, lq);
    }
}

extern "C" void kernel_launch(void* const* d_in, const int* in_sizes, int n_in,
                              void* d_out, int out_size, void* d_ws, size_t ws_size,
                              hipStream_t stream) {
    const int*   x     = (const int*)d_in[0];
    const float* emb   = (const float*)d_in[1];
    const float* Wih1  = (const float*)d_in[2];
    const float* Whh1  = (const float*)d_in[3];
    const float* bih1  = (const float*)d_in[4];
    const float* bhh1  = (const float*)d_in[5];
    const float* Wih2  = (const float*)d_in[6];
    const float* Whh2  = (const float*)d_in[7];
    const float* bih2  = (const float*)d_in[8];
    const float* bhh2  = (const float*)d_in[9];
    const float* fc1w  = (const float*)d_in[10];
    const float* fc1b  = (const float*)d_in[11];
    const float* fc2w  = (const float*)d_in[12];
    const float* fc2b  = (const float*)d_in[13];

    float* out1 = (float*)d_out;
    float* out2 = out1 + (size_t)16384 * 128;

    char* w = (char*)d_ws;
    unsigned int* flags = (unsigned int*)w;              //        512
    float*        U1    = (float*)(w + 512);             // 19,660,800
    _Float16*     H1    = (_Float16*)(w + 19661312);     // 10,485,760
    _Float16*     Wf1   = (_Float16*)(w + 30147072);     //  1,024,000
    _Float16*     Wf2   = (_Float16*)(w + 31171072);     //    204,800
    _Float16*     F1    = (_Float16*)(w + 31375872);     //     81,920
    _Float16*     F2    = (_Float16*)(w + 31457792);     //     81,920
    _Float16*     EMBF  = (_Float16*)(w + 31539712);     // 20,480,000 (read-only after prep)

    const int prep_blocks = (PREP_TOTAL8 + 255) / 256;
    k_prep<<<prep_blocks, 256, 0, stream>>>(emb, Wih1, Wih2, fc1w, fc2w,
                                            EMBF, Wf1, Wf2, F1, F2, flags);

    k_rec_fused<<<NREC + NGEMM, 512, LDS_BYTES, stream>>>(
        x, EMBF, Wf1, bih1, bhh1, U1, Whh1, Wf2, Whh2, bih2, bhh2, H1,
        F1, F2, fc1b, fc2b, out1, out2, flags);
}

// Round 8
// 804.815 us; speedup vs baseline: 2.1308x; 2.1308x over previous
//
#include <hip/hip_runtime.h>
#include <hip/hip_fp16.h>

#define S_LEN 512
#define BATCH 32
#define CHUNK 16

typedef _Float16 hv2  __attribute__((ext_vector_type(2)));
typedef _Float16 half8 __attribute__((ext_vector_type(8)));
typedef float    f32x4 __attribute__((ext_vector_type(4)));

__device__ __forceinline__ float dot2f(hv2 a, hv2 b, float c) {
#if __has_builtin(__builtin_amdgcn_fdot2)
    return __builtin_amdgcn_fdot2(a, b, c, false);
#else
    return c + (float)a.x * (float)b.x + (float)a.y * (float)b.y;
#endif
}

__device__ __forceinline__ float fast_tanh(float x) {
    float e = __expf(2.f * x);
    return 1.f - 2.f / (e + 1.f);
}

// Step barrier that does NOT drain vmcnt: LDS-only visibility.
__device__ __forceinline__ void lds_barrier() {
    __asm__ volatile("s_waitcnt lgkmcnt(0)\n\ts_barrier" ::: "memory");
}
__device__ __forceinline__ void vm_drain() {
    __asm__ volatile("s_waitcnt vmcnt(0)" ::: "memory");
}

// flags map (128 uints at workspace head):
//  [0..31]   producer progress (t) per batch
//  [64..95]  gemm per-chunk completion count (NGEMM => ready)
#define F_GC0 64

// ---------------------------------------------------------------------------
// Prep: convert to padded f16 (relu fused for emb). Zeroes flags.
// ---------------------------------------------------------------------------
#define E8   1280000   // 32000*320/8
#define W18  64000     // 320*1600/8
#define W28  12800     // 320*320/8
#define FF8  5120      // 128*320/8
#define PREP_TOTAL8 (E8 + W18 + W28 + FF8 + FF8)

__global__ __launch_bounds__(256) void k_prep(
    const float* __restrict__ emb,  const float* __restrict__ Wih1,
    const float* __restrict__ Wih2, const float* __restrict__ fc1w,
    const float* __restrict__ fc2w,
    _Float16* __restrict__ embf, _Float16* __restrict__ Wf1,
    _Float16* __restrict__ Wf2,  _Float16* __restrict__ F1,
    _Float16* __restrict__ F2,   unsigned int* __restrict__ flags)
{
    int gid = blockIdx.x * 256 + threadIdx.x;
    if (gid < 128) flags[gid] = 0u;
    if (gid >= PREP_TOTAL8) return;

    half8 v;
    _Float16* dst;

    if (gid < E8) {
        int row = gid / 40, c8 = (gid - row * 40) * 8;
        #pragma unroll
        for (int j = 0; j < 8; ++j) {
            int c = c8 + j;
            float f = (c < 300) ? emb[(size_t)row * 300 + c] : 0.f;
            v[j] = (_Float16)(f > 0.f ? f : 0.f);
        }
        dst = embf + (size_t)gid * 8;
    } else if (gid < E8 + W18) {
        int i = gid - E8;
        int row = i / 200, c8 = (i - row * 200) * 8;
        #pragma unroll
        for (int j = 0; j < 8; ++j) {
            int c = c8 + j, w = c / 320, cc = c - w * 320;
            float f = (row < 300 && cc < 300) ? Wih1[(size_t)row * 1500 + w * 300 + cc] : 0.f;
            v[j] = (_Float16)f;
        }
        dst = Wf1 + (size_t)i * 8;
    } else if (gid < E8 + W18 + W28) {
        int i = gid - E8 - W18;
        int row = i / 40, c8 = (i - row * 40) * 8;
        #pragma unroll
        for (int j = 0; j < 8; ++j) {
            int c = c8 + j;
            float f = (row < 300 && c < 300) ? Wih2[(size_t)row * 300 + c] : 0.f;
            v[j] = (_Float16)f;
        }
        dst = Wf2 + (size_t)i * 8;
    } else if (gid < E8 + W18 + W28 + FF8) {
        int i = gid - E8 - W18 - W28;
        int row = i / 40, c8 = (i - row * 40) * 8;
        #pragma unroll
        for (int j = 0; j < 8; ++j) {
            int c = c8 + j;
            v[j] = (_Float16)((c < 300) ? fc1w[(size_t)row * 300 + c] : 0.f);
        }
        dst = F1 + (size_t)i * 8;
    } else {
        int i = gid - E8 - W18 - W28 - FF8;
        int row = i / 40, c8 = (i - row * 40) * 8;
        #pragma unroll
        for (int j = 0; j < 8; ++j) {
            int c = c8 + j;
            v[j] = (_Float16)((c < 300) ? fc2w[(size_t)row * 300 + c] : 0.f);
        }
        dst = F2 + (size_t)i * 8;
    }
    *(half8*)dst = v;
}

// ---------------------------------------------------------------------------
// Fused pipeline kernel. 140 blocks x 512 threads, all co-resident.
//  Blocks 0..31  : producer, layer 1 (per-batch) + fused fc1 epilogue.
//  Blocks 32..63 : consumer, layer 2 (per-batch) + fused fc2 epilogue.
//  Blocks 64..139: GEMM1 persistent chunk-sweep. 76 blocks x 8 waves = 608
//                  waves = exactly the 32 m-tiles x 19 n-tiles of one chunk;
//                  each wave owns ONE 16x16 tile (K=1600) and sweeps chunks
//                  c=0..31 IN ORDER, so chunk c is done at ~ (c+1)*T_gemm/32
//                  (~4us each) — always ahead of the producer's 19.5us/chunk
//                  pace. No throttle (R7 lesson: chunk latency must not be a
//                  whole tile-block's latency). nt = g%19 -> each block's
//                  B-slice (51KB of Wf1) is cache-hot across all 32 chunks.
// H2 never touches global memory (fc2 reads the LDS h-ring); EMBF is
// read-only after prep — no alias hazard.
// ---------------------------------------------------------------------------
#define LDS_BYTES 52096
#define NREC 64
#define NGEMM 76

__device__ __forceinline__ void load_u_regs(float* up, const float* __restrict__ U1,
                                            int b, int t0) {
    #pragma unroll
    for (int j = 0; j < 10; ++j) {
        int e = threadIdx.x + 512 * j;
        int row = e / 300, col = e - row * 300;
        up[j] = (e < 4800) ? U1[((size_t)((t0 + row) * BATCH + b)) * 300 + col] : 0.f;
    }
}

__device__ __forceinline__ void wait_gemm(unsigned int* flags, int c) {
    if (threadIdx.x == 0) {
        while (__hip_atomic_load(&flags[F_GC0 + c], __ATOMIC_ACQUIRE,
                                 __HIP_MEMORY_SCOPE_AGENT) < (unsigned)NGEMM)
            __builtin_amdgcn_s_sleep(2);
    }
    __syncthreads();
}

// Fused FC epilogue: out rows (b*512 + tb + 0..15) x 128 cols from the LDS
// h-ring. Same MFMA layout as the proven k_fc kernel.
__device__ __forceinline__ void fc_epilogue(
    const _Float16 (*hc)[320], const _Float16* __restrict__ F,
    const float* __restrict__ fb, float* __restrict__ out,
    int b, int tb, int wid, int lm, int lq)
{
    f32x4 acc = (f32x4){0.f, 0.f, 0.f, 0.f};
    const int n = wid * 16 + lm;
    const _Float16* frow = F + (size_t)n * 320;
    #pragma unroll
    for (int k0 = 0; k0 < 320; k0 += 32) {
        half8 a  = *(const half8*)&hc[lm][k0 + lq * 8];
        half8 bf = *(const half8*)&frow[k0 + lq * 8];
        acc = __builtin_amdgcn_mfma_f32_16x16x32_f16(a, bf, acc, 0, 0, 0);
    }
    const float bv = fb[n];
    #pragma unroll
    for (int reg = 0; reg < 4; ++reg) {
        const int t = tb + lq * 4 + reg;
        out[(size_t)(b * 512 + t) * 128 + n] = acc[reg] + bv;
    }
}

__global__ __launch_bounds__(512) void k_rec_fused(
    const int* __restrict__ x, const _Float16* __restrict__ embf,
    const _Float16* __restrict__ Wf1,
    const float* __restrict__ bih1, const float* __restrict__ bhh1,
    float* __restrict__ U1, const float* __restrict__ Whh1,
    const _Float16* __restrict__ Wf2, const float* __restrict__ Whh2,
    const float* __restrict__ bih2, const float* __restrict__ bhh2,
    _Float16* __restrict__ H1f,
    const _Float16* __restrict__ F1, const _Float16* __restrict__ F2,
    const float* __restrict__ fb1, const float* __restrict__ fb2,
    float* __restrict__ out1, float* __restrict__ out2,
    unsigned int* __restrict__ flags)
{
    const int tid  = threadIdx.x;

    if (blockIdx.x >= NREC) {
        // ============ GEMM1 role: persistent chunk-sweep ============
        const int g    = blockIdx.x - NREC;   // 0..75
        const int wv   = tid >> 6;            // 0..7
        const int lane = tid & 63;
        const int m    = lane & 15;
        const int q    = lane >> 4;
        const int nt   = g % 19;              // n-tile: B-slice hot across chunks
        const int mtg  = g / 19;              // 0..3
        const int mt   = mtg * 8 + wv;        // m-tile 0..31
        const int n    = nt * 16 + m;         // B row = D col (n<304<320: padded)
        const _Float16* wrowB = Wf1 + (size_t)n * 1600;
        const float bias = (n < 300) ? (bih1[n] + bhh1[n]) : 0.f;

        for (int c = 0; c < 32; ++c) {
            const int r  = c * 512 + mt * 16 + m;          // A row for this lane
            const int xb = ((r & 31) * S_LEN + (r >> 5)) * 5;
            f32x4 acc = (f32x4){0.f, 0.f, 0.f, 0.f};
            #pragma unroll
            for (int w = 0; w < 5; ++w) {
                const int idx = x[xb + w];
                const _Float16* ea = embf + (size_t)idx * 320;
                const _Float16* wb = wrowB + w * 320;
                #pragma unroll
                for (int cc = 0; cc < 10; ++cc) {
                    half8 a  = *(const half8*)(ea + cc * 32 + q * 8);
                    half8 bf = *(const half8*)(wb + cc * 32 + q * 8);
                    acc = __builtin_amdgcn_mfma_f32_16x16x32_f16(a, bf, acc, 0, 0, 0);
                }
            }
            if (n < 300) {
                #pragma unroll
                for (int reg = 0; reg < 4; ++reg) {
                    const int rr = c * 512 + mt * 16 + q * 4 + reg;
                    U1[(size_t)rr * 300 + n] = acc[reg] + bias;
                }
            }
            vm_drain();        // own stores complete
            __syncthreads();   // all 8 waves' stores complete
            if (tid == 0)
                __hip_atomic_fetch_add(&flags[F_GC0 + c], 1u,
                                       __ATOMIC_RELEASE, __HIP_MEMORY_SCOPE_AGENT);
        }
        return;
    }

    extern __shared__ char smem[];
    float   (*partials)[304] = (float(*)[304])smem;
    _Float16 (*hc)[320]      = (_Float16(*)[320])(smem + 12160);
    float   (*uc)[304]       = (float(*)[304])(smem + 22400);
    _Float16 (*h1s)[320]     = (_Float16(*)[320])(smem + 41856);

    const bool comp = tid < 500;
    const int g    = comp ? tid / 50 : 0;
    const int rt   = comp ? tid % 50 : 0;
    const int lane = tid & 63;
    const int wid  = tid >> 6;
    const int lm   = lane & 15;
    const int lq   = lane >> 4;

    // zero h ring (slot 15 = h_{-1} = 0; pad cols stay 0 forever)
    for (int i = tid; i < CHUNK * 320; i += 512)
        ((_Float16*)hc)[i] = (_Float16)0.f;

    if (blockIdx.x < 32) {
        // ========================= producer: layer 1 + fc1 =========================
        const int b = blockIdx.x;
        hv2 w1[6][16];
        if (comp) {
            #pragma unroll
            for (int i = 0; i < 6; ++i) {
                const float* wr = Whh1 + (size_t)(rt + 50 * i) * 300 + g * 32;
                #pragma unroll
                for (int j = 0; j < 16; ++j) {
                    int c0 = g * 32 + 2 * j;
                    hv2 p;
                    p.x = (c0     < 300) ? (_Float16)wr[2 * j]     : (_Float16)0.f;
                    p.y = (c0 + 1 < 300) ? (_Float16)wr[2 * j + 1] : (_Float16)0.f;
                    w1[i][j] = p;
                }
            }
        }

        wait_gemm(flags, 0);
        float upref[10];
        load_u_regs(upref, U1, b, 0);

        for (int c = 0; c < 32; ++c) {
            const int t0 = c * CHUNK;
            if (c > 0) {
                // bulk-store previous chunk's H1 + fused fc1 on the same chunk
                const int tb = t0 - CHUNK;
                for (int i = tid; i < CHUNK * 40; i += 512) {
                    int row = i / 40, c8 = i - row * 40;
                    half8 v = *(const half8*)&hc[row][c8 * 8];
                    *(half8*)&H1f[((size_t)((tb + row) * BATCH + b)) * 320 + c8 * 8] = v;
                }
                fc_epilogue(hc, F1, fb1, out1, b, tb, wid, lm, lq);
            }
            // stage this chunk's U into LDS from prefetch regs
            #pragma unroll
            for (int j = 0; j < 10; ++j) {
                int e = tid + 512 * j;
                if (e < 4800) {
                    int row = e / 300, col = e - row * 300;
                    uc[row][col] = upref[j];
                }
            }
            if (c > 0) {
                vm_drain();       // own H1 stores complete
                __syncthreads();  // all waves' stores complete before release
                if (tid == 0)
                    __hip_atomic_store(&flags[b], (unsigned)t0,
                                       __ATOMIC_RELEASE, __HIP_MEMORY_SCOPE_AGENT);
            }
            if (c + 1 < 32) {
                wait_gemm(flags, c + 1);                 // U1 chunk c+1 ready?
                load_u_regs(upref, U1, b, t0 + CHUNK);   // in flight across steps
            }
            lds_barrier();

            for (int s = 0; s < CHUNK; ++s) {
                if (comp) {
                    const half8* hp = (const half8*)&hc[(s - 1) & 15][g * 32];
                    float a0 = 0.f, a1 = 0.f, a2 = 0.f, a3 = 0.f, a4 = 0.f, a5 = 0.f;
                    #pragma unroll
                    for (int jj = 0; jj < 4; ++jj) {
                        half8 q8 = hp[jj];
                        const hv2* qv = (const hv2*)&q8;
                        #pragma unroll
                        for (int j4 = 0; j4 < 4; ++j4) {
                            const int j = 4 * jj + j4;
                            a0 = dot2f(w1[0][j], qv[j4], a0);
                            a1 = dot2f(w1[1][j], qv[j4], a1);
                            a2 = dot2f(w1[2][j], qv[j4], a2);
                            a3 = dot2f(w1[3][j], qv[j4], a3);
                            a4 = dot2f(w1[4][j], qv[j4], a4);
                            a5 = dot2f(w1[5][j], qv[j4], a5);
                        }
                    }
                    partials[g][rt]       = a0;
                    partials[g][rt + 50]  = a1;
                    partials[g][rt + 100] = a2;
                    partials[g][rt + 150] = a3;
                    partials[g][rt + 200] = a4;
                    partials[g][rt + 250] = a5;
                }
                lds_barrier();
                if (tid < 300) {
                    float ssum = uc[s][tid];
                    #pragma unroll
                    for (int g2 = 0; g2 < 10; ++g2)
                        ssum += partials[g2][tid];
                    hc[s][tid] = (_Float16)fast_tanh(ssum);
                }
                lds_barrier();
            }
        }
        // final chunk: store H1, flag, fused fc1
        {
            const int tb = S_LEN - CHUNK;
            for (int i = tid; i < CHUNK * 40; i += 512) {
                int row = i / 40, c8 = i - row * 40;
                half8 v = *(const half8*)&hc[row][c8 * 8];
                *(half8*)&H1f[((size_t)((tb + row) * BATCH + b)) * 320 + c8 * 8] = v;
            }
            fc_epilogue(hc, F1, fb1, out1, b, tb, wid, lm, lq);
            vm_drain();
            __syncthreads();
            if (tid == 0)
                __hip_atomic_store(&flags[b], (unsigned)S_LEN,
                                   __ATOMIC_RELEASE, __HIP_MEMORY_SCOPE_AGENT);
        }
    } else {
        // ========================= consumer: layer 2 + fc2 =========================
        const int b = blockIdx.x - 32;
        hv2 whh[6][16];
        if (comp) {
            #pragma unroll
            for (int i = 0; i < 6; ++i) {
                const float* wr = Whh2 + (size_t)(rt + 50 * i) * 300 + g * 32;
                #pragma unroll
                for (int j = 0; j < 16; ++j) {
                    int c0 = g * 32 + 2 * j;
                    hv2 p;
                    p.x = (c0     < 300) ? (_Float16)wr[2 * j]     : (_Float16)0.f;
                    p.y = (c0 + 1 < 300) ? (_Float16)wr[2 * j + 1] : (_Float16)0.f;
                    whh[i][j] = p;
                }
            }
        }
        float bias = (tid < 300) ? (bih2[tid] + bhh2[tid]) : 0.f;

        for (int c = 0; c < 32; ++c) {
            const int t0 = c * CHUNK;
            if (c > 0) {
                // fused fc2 on previous chunk's h2 (still in hc ring);
                // runs before the producer poll, so it's hidden under the wait
                fc_epilogue(hc, F2, fb2, out2, b, t0 - CHUNK, wid, lm, lq);
            }
            if (tid == 0) {
                while (__hip_atomic_load(&flags[b], __ATOMIC_ACQUIRE,
                                         __HIP_MEMORY_SCOPE_AGENT) < (unsigned)(t0 + CHUNK))
                    __builtin_amdgcn_s_sleep(2);
            }
            __syncthreads();   // orders after poll

            // stage this chunk's h1 into LDS
            for (int i = tid; i < CHUNK * 40; i += 512) {
                int row = i / 40, c8 = i - row * 40;
                *(half8*)&h1s[row][c8 * 8] =
                    *(const half8*)&H1f[((size_t)((t0 + row) * BATCH + b)) * 320 + c8 * 8];
            }
            lds_barrier();

            // U2-chunk = h1s @ Wf2^T via MFMA (M=16 steps, N=304, K=320)
            for (int nt = wid; nt < 19; nt += 8) {
                f32x4 acc = (f32x4){0.f, 0.f, 0.f, 0.f};
                const int n = nt * 16 + lm;
                const _Float16* wrow = Wf2 + (size_t)n * 320;
                #pragma unroll
                for (int k0 = 0; k0 < 320; k0 += 32) {
                    half8 a  = *(const half8*)&h1s[lm][k0 + lq * 8];
                    half8 bf = *(const half8*)&wrow[k0 + lq * 8];
                    acc = __builtin_amdgcn_mfma_f32_16x16x32_f16(a, bf, acc, 0, 0, 0);
                }
                #pragma unroll
                for (int reg = 0; reg < 4; ++reg)
                    uc[lq * 4 + reg][n] = acc[reg];
            }
            lds_barrier();

            for (int s = 0; s < CHUNK; ++s) {
                if (comp) {
                    const half8* hp = (const half8*)&hc[(s - 1) & 15][g * 32];
                    float a0 = 0.f, a1 = 0.f, a2 = 0.f, a3 = 0.f, a4 = 0.f, a5 = 0.f;
                    #pragma unroll
                    for (int jj = 0; jj < 4; ++jj) {
                        half8 q8 = hp[jj];
                        const hv2* qv = (const hv2*)&q8;
                        #pragma unroll
                        for (int j4 = 0; j4 < 4; ++j4) {
                            const int j = 4 * jj + j4;
                            a0 = dot2f(whh[0][j], qv[j4], a0);
                            a1 = dot2f(whh[1][j], qv[j4], a1);
                            a2 = dot2f(whh[2][j], qv[j4], a2);
                            a3 = dot2f(whh[3][j], qv[j4], a3);
                            a4 = dot2f(whh[4][j], qv[j4], a4);
                            a5 = dot2f(whh[5][j], qv[j4], a5);
                        }
                    }
                    partials[g][rt]       = a0;
                    partials[g][rt + 50]  = a1;
                    partials[g][rt + 100] = a2;
                    partials[g][rt + 150] = a3;
                    partials[g][rt + 200] = a4;
                    partials[g][rt + 250] = a5;
                }
                lds_barrier();
                if (tid < 300) {
                    float ssum = bias + uc[s][tid];
                    #pragma unroll
                    for (int g2 = 0; g2 < 10; ++g2)
                        ssum += partials[g2][tid];
                    hc[s][tid] = (_Float16)fast_tanh(ssum);
                }
                lds_barrier();
            }
        }
        // final chunk: fused fc2 (h2 chunk 31 in hc ring)
        fc_epilogue(hc, F2, fb2, out2, b, S_LEN - CHUNK, wid, lm, lq);
    }
}

extern "C" void kernel_launch(void* const* d_in, const int* in_sizes, int n_in,
                              void* d_out, int out_size, void* d_ws, size_t ws_size,
                              hipStream_t stream) {
    const int*   x     = (const int*)d_in[0];
    const float* emb   = (const float*)d_in[1];
    const float* Wih1  = (const float*)d_in[2];
    const float* Whh1  = (const float*)d_in[3];
    const float* bih1  = (const float*)d_in[4];
    const float* bhh1  = (const float*)d_in[5];
    const float* Wih2  = (const float*)d_in[6];
    const float* Whh2  = (const float*)d_in[7];
    const float* bih2  = (const float*)d_in[8];
    const float* bhh2  = (const float*)d_in[9];
    const float* fc1w  = (const float*)d_in[10];
    const float* fc1b  = (const float*)d_in[11];
    const float* fc2w  = (const float*)d_in[12];
    const float* fc2b  = (const float*)d_in[13];

    float* out1 = (float*)d_out;
    float* out2 = out1 + (size_t)16384 * 128;

    char* w = (char*)d_ws;
    unsigned int* flags = (unsigned int*)w;              //        512
    float*        U1    = (float*)(w + 512);             // 19,660,800
    _Float16*     H1    = (_Float16*)(w + 19661312);     // 10,485,760
    _Float16*     Wf1   = (_Float16*)(w + 30147072);     //  1,024,000
    _Float16*     Wf2   = (_Float16*)(w + 31171072);     //    204,800
    _Float16*     F1    = (_Float16*)(w + 31375872);     //     81,920
    _Float16*     F2    = (_Float16*)(w + 31457792);     //     81,920
    _Float16*     EMBF  = (_Float16*)(w + 31539712);     // 20,480,000 (read-only after prep)

    const int prep_blocks = (PREP_TOTAL8 + 255) / 256;
    k_prep<<<prep_blocks, 256, 0, stream>>>(emb, Wih1, Wih2, fc1w, fc2w,
                                            EMBF, Wf1, Wf2, F1, F2, flags);

    k_rec_fused<<<NREC + NGEMM, 512, LDS_BYTES, stream>>>(
        x, EMBF, Wf1, bih1, bhh1, U1, Whh1, Wf2, Whh2, bih2, bhh2, H1,
        F1, F2, fc1b, fc2b, out1, out2, flags);
}